// Round 1
// baseline (2559.929 us; speedup 1.0000x reference)
//
#include <hip/hip_runtime.h>
#include <hip/hip_bf16.h>
#include <math.h>

#define N_NODES 100000
#define E_EDGES 3200000
#define IN_DIM  256

// ---------------- BN column stats (sum, sumsq per feature) ----------------
__global__ __launch_bounds__(256) void bn_stats_kernel(
    const float* __restrict__ x, float* __restrict__ sums /*512 floats*/) {
  int c = threadIdx.x;  // 0..255 feature
  float s = 0.f, s2 = 0.f;
  for (int r = blockIdx.x; r < N_NODES; r += gridDim.x) {
    float v = x[(size_t)r * IN_DIM + c];
    s += v; s2 += v * v;
  }
  atomicAdd(&sums[c], s);
  atomicAdd(&sums[256 + c], s2);
}

// ------------- fold BN affine into W_in / b_in:  W'=diag(s)W, b'=b_in+t@W ----
__global__ __launch_bounds__(256) void fold_bn_kernel(
    const float* __restrict__ sums, const float* __restrict__ bn_g,
    const float* __restrict__ bn_b, const float* __restrict__ W_in,
    const float* __restrict__ b_in, float* __restrict__ Wf,
    float* __restrict__ bf) {
  int j = blockIdx.x;   // out col 0..139
  int c = threadIdx.x;  // in col 0..255
  const float invN = 1.0f / (float)N_NODES;
  float mu  = sums[c] * invN;
  float var = sums[256 + c] * invN - mu * mu;
  float s   = bn_g[c] * rsqrtf(var + 1e-5f);
  float t   = bn_b[c] - mu * s;
  float w   = W_in[(size_t)c * 140 + j];
  Wf[(size_t)c * 140 + j] = s * w;
  float v = t * w;
  // reduce v over 256 threads
  for (int o = 32; o > 0; o >>= 1) v += __shfl_down(v, o, 64);
  __shared__ float red[4];
  int wid = threadIdx.x >> 6, lane = threadIdx.x & 63;
  if (lane == 0) red[wid] = v;
  __syncthreads();
  if (threadIdx.x == 0)
    bf[j] = b_in[j] + red[0] + red[1] + red[2] + red[3];
}

// ---------------- CSR row_ptr from sorted rows (binary search) -------------
__global__ __launch_bounds__(256) void build_rowptr_kernel(
    const int* __restrict__ rows, int* __restrict__ rowptr) {
  int r = blockIdx.x * 256 + threadIdx.x;
  if (r > N_NODES) return;
  int lo = 0, hi = E_EDGES;
  while (lo < hi) {
    int mid = (lo + hi) >> 1;
    if (rows[mid] < r) lo = mid + 1; else hi = mid;
  }
  rowptr[r] = lo;
}

// ---------------- generic fp32 GEMM: C = act(A[N,K] @ W[K,M] (+bias)) ------
// block: 256 thr = 16(tx: col groups) x 16(ty: row groups); tile 128 rows.
// per-thread: 8 rows x CT cols register tile.
template <int CT>
__global__ __launch_bounds__(256) void gemm_kernel(
    const float* __restrict__ A, const float* __restrict__ W,
    const float* __restrict__ bias, float* __restrict__ C,
    int K, int M, int lda, int ldc, int act) {
  __shared__ float As[128 * 65];        // [row][k], pad 65 -> conflict-free
  __shared__ float Ws[64 * 140 + 160];  // flat [k*M + col], slack for OOB cols
  int tid = threadIdx.x;
  int tx = tid & 15, ty = tid >> 4;
  int rbase = blockIdx.x * 128;

  float acc[8][CT];
#pragma unroll
  for (int i = 0; i < 8; ++i)
#pragma unroll
    for (int j = 0; j < CT; ++j) acc[i][j] = 0.f;

  for (int k0 = 0; k0 < K; k0 += 64) {
    int kc = min(64, K - k0);
    // stage A tile: 128 rows x kc floats (float4 global, scalar LDS stores)
#pragma unroll
    for (int it = 0; it < 8; ++it) {
      int idx = tid + it * 256;       // 0..2047
      int r = idx >> 4, q = idx & 15; // q: float4 index within row
      float4 v = make_float4(0.f, 0.f, 0.f, 0.f);
      int row = rbase + r;
      if (row < N_NODES && q * 4 < kc)
        v = *(const float4*)&A[(size_t)row * lda + k0 + q * 4];
      float* dst = &As[r * 65 + q * 4];
      dst[0] = v.x; dst[1] = v.y; dst[2] = v.z; dst[3] = v.w;
    }
    // stage W chunk: rows k0..k0+kc contiguous
    for (int idx = tid; idx < kc * M; idx += 256)
      Ws[idx] = W[(size_t)k0 * M + idx];
    __syncthreads();

    for (int k = 0; k < kc; ++k) {
      float a[8];
#pragma unroll
      for (int i = 0; i < 8; ++i) a[i] = As[(ty * 8 + i) * 65 + k];
      float w[CT];
#pragma unroll
      for (int j = 0; j < CT; ++j) w[j] = Ws[k * M + tx * CT + j];
#pragma unroll
      for (int i = 0; i < 8; ++i)
#pragma unroll
        for (int j = 0; j < CT; ++j)
          acc[i][j] = fmaf(a[i], w[j], acc[i][j]);
    }
    __syncthreads();
  }

  // epilogue
#pragma unroll
  for (int i = 0; i < 8; ++i) {
    int row = rbase + ty * 8 + i;
    if (row >= N_NODES) continue;
#pragma unroll
    for (int j = 0; j < CT; ++j) {
      int col = tx * CT + j;
      if (col >= M) continue;
      float c = acc[i][j];
      if (bias) c += bias[col];
      if (act) c = tanhf(c);
      C[(size_t)row * ldc + col] = c;
    }
  }
}

// ---------------- SPMM: out[r,:] = sum_e vals[e] * in[cols[e],:] -----------
// 32 lanes per row (lane = float4 column), 8 rows per 256-thr block.
template <int F>
__global__ __launch_bounds__(256) void spmm_kernel(
    const int* __restrict__ rowptr, const int* __restrict__ cols,
    const float* __restrict__ vals, const float* __restrict__ xin,
    float* __restrict__ xout) {
  constexpr int F4 = F / 4;
  int lane = threadIdx.x & 31;
  int yrow = threadIdx.x >> 5;
  int r = blockIdx.x * 8 + yrow;
  if (r >= N_NODES) return;
  int e0 = rowptr[r], e1 = rowptr[r + 1];
  if (lane >= F4) return;
  float4 acc  = make_float4(0.f, 0.f, 0.f, 0.f);
  float4 acc2 = make_float4(0.f, 0.f, 0.f, 0.f);
  int e = e0;
  for (; e + 1 < e1; e += 2) {
    float v0 = vals[e];     int c0 = cols[e];
    float v1 = vals[e + 1]; int c1 = cols[e + 1];
    float4 x0 = *(const float4*)&xin[(size_t)c0 * F + lane * 4];
    float4 x1 = *(const float4*)&xin[(size_t)c1 * F + lane * 4];
    acc.x  = fmaf(v0, x0.x, acc.x);  acc.y  = fmaf(v0, x0.y, acc.y);
    acc.z  = fmaf(v0, x0.z, acc.z);  acc.w  = fmaf(v0, x0.w, acc.w);
    acc2.x = fmaf(v1, x1.x, acc2.x); acc2.y = fmaf(v1, x1.y, acc2.y);
    acc2.z = fmaf(v1, x1.z, acc2.z); acc2.w = fmaf(v1, x1.w, acc2.w);
  }
  if (e < e1) {
    float v0 = vals[e]; int c0 = cols[e];
    float4 x0 = *(const float4*)&xin[(size_t)c0 * F + lane * 4];
    acc.x = fmaf(v0, x0.x, acc.x); acc.y = fmaf(v0, x0.y, acc.y);
    acc.z = fmaf(v0, x0.z, acc.z); acc.w = fmaf(v0, x0.w, acc.w);
  }
  acc.x += acc2.x; acc.y += acc2.y; acc.z += acc2.z; acc.w += acc2.w;
  *(float4*)&xout[(size_t)r * F + lane * 4] = acc;
}

// ---------------- bias + LayerNorm + tanh (one wave per row) ---------------
template <int F>
__global__ __launch_bounds__(256) void bias_ln_tanh_kernel(
    const float* __restrict__ in, const float* __restrict__ bias,
    const float* __restrict__ g, const float* __restrict__ b,
    float* __restrict__ out) {
  int wid = threadIdx.x >> 6, lane = threadIdx.x & 63;
  int r = blockIdx.x * 4 + wid;
  if (r >= N_NODES) return;
  float x0 = 0.f, x1 = 0.f;
  if (lane < F)      x0 = in[(size_t)r * F + lane] + bias[lane];
  if (lane + 64 < F) x1 = in[(size_t)r * F + lane + 64] + bias[lane + 64];
  float s = x0 + x1, s2 = x0 * x0 + x1 * x1;
  for (int o = 32; o > 0; o >>= 1) {
    s  += __shfl_down(s, o, 64);
    s2 += __shfl_down(s2, o, 64);
  }
  s = __shfl(s, 0, 64); s2 = __shfl(s2, 0, 64);
  const float invF = 1.0f / (float)F;
  float mu = s * invF;
  float var = s2 * invF - mu * mu;
  float rs = rsqrtf(var + 1e-5f);
  if (lane < F)
    out[(size_t)r * F + lane] = tanhf((x0 - mu) * rs * g[lane] + b[lane]);
  if (lane + 64 < F)
    out[(size_t)r * F + lane + 64] =
        tanhf((x1 - mu) * rs * g[lane + 64] + b[lane + 64]);
}

// ---------------------------------------------------------------------------
extern "C" void kernel_launch(void* const* d_in, const int* in_sizes, int n_in,
                              void* d_out, int out_size, void* d_ws,
                              size_t ws_size, hipStream_t stream) {
  const float* x        = (const float*)d_in[0];
  const float* adj_vals = (const float*)d_in[1];
  const float* bn_g     = (const float*)d_in[2];
  const float* bn_b     = (const float*)d_in[3];
  const float* W_in     = (const float*)d_in[4];
  const float* b_in     = (const float*)d_in[5];
  const float* W1       = (const float*)d_in[6];
  const float* b1       = (const float*)d_in[7];
  const float* ln1_g    = (const float*)d_in[8];
  const float* ln1_b    = (const float*)d_in[9];
  const float* W2       = (const float*)d_in[10];
  const float* b2       = (const float*)d_in[11];
  const float* ln2_g    = (const float*)d_in[12];
  const float* ln2_b    = (const float*)d_in[13];
  const float* W_out    = (const float*)d_in[14];
  const float* b_out    = (const float*)d_in[15];
  const int*   adj_rows = (const int*)d_in[16];
  const int*   adj_cols = (const int*)d_in[17];
  float* out = (float*)d_out;

  // workspace layout (floats)
  float* ws      = (float*)d_ws;
  float* bn_sums = ws;                       // 512
  float* Wf      = ws + 512;                 // 256*140 = 35840
  float* bf      = Wf + 35840;               // 144
  int*   rowptr  = (int*)(bf + 144);         // 100001 -> pad to 100016
  float* buf0    = (float*)(rowptr + 100016);        // N*140
  float* buf1    = buf0 + (size_t)N_NODES * 140;     // N*120

  hipMemsetAsync(bn_sums, 0, 512 * sizeof(float), stream);
  bn_stats_kernel<<<1024, 256, 0, stream>>>(x, bn_sums);
  fold_bn_kernel<<<140, 256, 0, stream>>>(bn_sums, bn_g, bn_b, W_in, b_in, Wf, bf);
  build_rowptr_kernel<<<(N_NODES + 256) / 256, 256, 0, stream>>>(adj_rows, rowptr);

  const int gemm_grid = (N_NODES + 127) / 128;  // 782
  const int spmm_grid = (N_NODES + 7) / 8;      // 12500
  const int ln_grid   = (N_NODES + 3) / 4;      // 25000

  // t = tanh(bn(x) @ W_in + b_in)   [N,140]  (BN folded into Wf/bf)
  gemm_kernel<9><<<gemm_grid, 256, 0, stream>>>(x, Wf, bf, buf0, 256, 140, 256, 140, 1);
  // z = t @ W1 (bias deferred)      [N,120]
  gemm_kernel<8><<<gemm_grid, 256, 0, stream>>>(buf0, W1, nullptr, buf1, 140, 120, 140, 120, 0);
  // 4 hops at F=120:  (A^4 h)W1 == A^4 (h W1)
  spmm_kernel<120><<<spmm_grid, 256, 0, stream>>>(rowptr, adj_cols, adj_vals, buf1, buf0);
  spmm_kernel<120><<<spmm_grid, 256, 0, stream>>>(rowptr, adj_cols, adj_vals, buf0, buf1);
  spmm_kernel<120><<<spmm_grid, 256, 0, stream>>>(rowptr, adj_cols, adj_vals, buf1, buf0);
  spmm_kernel<120><<<spmm_grid, 256, 0, stream>>>(rowptr, adj_cols, adj_vals, buf0, buf1);
  // u = tanh(LN(z + b1))            [N,120]
  bias_ln_tanh_kernel<120><<<ln_grid, 256, 0, stream>>>(buf1, b1, ln1_g, ln1_b, buf0);
  // v = u @ W2 (bias deferred)      [N,100]
  gemm_kernel<7><<<gemm_grid, 256, 0, stream>>>(buf0, W2, nullptr, buf1, 120, 100, 120, 100, 0);
  // 4 hops at F=100
  spmm_kernel<100><<<spmm_grid, 256, 0, stream>>>(rowptr, adj_cols, adj_vals, buf1, buf0);
  spmm_kernel<100><<<spmm_grid, 256, 0, stream>>>(rowptr, adj_cols, adj_vals, buf0, buf1);
  spmm_kernel<100><<<spmm_grid, 256, 0, stream>>>(rowptr, adj_cols, adj_vals, buf1, buf0);
  spmm_kernel<100><<<spmm_grid, 256, 0, stream>>>(rowptr, adj_cols, adj_vals, buf0, buf1);
  // w = tanh(LN(v + b2))            [N,100]
  bias_ln_tanh_kernel<100><<<ln_grid, 256, 0, stream>>>(buf1, b2, ln2_g, ln2_b, buf0);
  // out = w @ W_out + b_out         [N,64]
  gemm_kernel<4><<<gemm_grid, 256, 0, stream>>>(buf0, W_out, b_out, out, 100, 64, 100, 64, 0);
}

// Round 2
// 1976.033 us; speedup vs baseline: 1.2955x; 1.2955x over previous
//
#include <hip/hip_runtime.h>
#include <hip/hip_bf16.h>
#include <math.h>

#define N_NODES 100000
#define E_EDGES 3200000
#define IN_DIM  256

// ---- bf16 helpers ---------------------------------------------------------
__device__ __forceinline__ unsigned short f2bf(float f) {
  unsigned u = __float_as_uint(f);
  u += 0x7fffu + ((u >> 16) & 1u);   // RTNE
  return (unsigned short)(u >> 16);
}
__device__ __forceinline__ float bf2f(unsigned short h) {
  return __uint_as_float(((unsigned)h) << 16);
}

// ---------------- BN column stats (sum, sumsq per feature) ----------------
__global__ __launch_bounds__(256) void bn_stats_kernel(
    const float* __restrict__ x, float* __restrict__ sums /*512 floats*/) {
  int c = threadIdx.x;  // 0..255 feature
  float s = 0.f, s2 = 0.f;
  for (int r = blockIdx.x; r < N_NODES; r += gridDim.x) {
    float v = x[(size_t)r * IN_DIM + c];
    s += v; s2 += v * v;
  }
  atomicAdd(&sums[c], s);
  atomicAdd(&sums[256 + c], s2);
}

// ------------- fold BN affine into W_in / b_in ----------------------------
__global__ __launch_bounds__(256) void fold_bn_kernel(
    const float* __restrict__ sums, const float* __restrict__ bn_g,
    const float* __restrict__ bn_b, const float* __restrict__ W_in,
    const float* __restrict__ b_in, float* __restrict__ Wf,
    float* __restrict__ bf) {
  int j = blockIdx.x;   // out col 0..139
  int c = threadIdx.x;  // in col 0..255
  const float invN = 1.0f / (float)N_NODES;
  float mu  = sums[c] * invN;
  float var = sums[256 + c] * invN - mu * mu;
  float s   = bn_g[c] * rsqrtf(var + 1e-5f);
  float t   = bn_b[c] - mu * s;
  float w   = W_in[(size_t)c * 140 + j];
  Wf[(size_t)c * 140 + j] = s * w;
  float v = t * w;
  for (int o = 32; o > 0; o >>= 1) v += __shfl_down(v, o, 64);
  __shared__ float red[4];
  int wid = threadIdx.x >> 6, lane = threadIdx.x & 63;
  if (lane == 0) red[wid] = v;
  __syncthreads();
  if (threadIdx.x == 0)
    bf[j] = b_in[j] + red[0] + red[1] + red[2] + red[3];
}

// ---------------- CSR row_ptr from sorted rows (binary search) -------------
__global__ __launch_bounds__(256) void build_rowptr_kernel(
    const int* __restrict__ rows, int* __restrict__ rowptr) {
  int r = blockIdx.x * 256 + threadIdx.x;
  if (r > N_NODES) return;
  int lo = 0, hi = E_EDGES;
  while (lo < hi) {
    int mid = (lo + hi) >> 1;
    if (rows[mid] < r) lo = mid + 1; else hi = mid;
  }
  rowptr[r] = lo;
}

// ---------------- generic fp32 GEMM: C = act(A[N,K] @ W[K,M] (+bias)) ------
// outfmt: 0 = fp32 C, 1 = bf16 C (ushort rows, stride ldc)
template <int CT>
__global__ __launch_bounds__(256) void gemm_kernel(
    const float* __restrict__ A, const float* __restrict__ W,
    const float* __restrict__ bias, void* __restrict__ C,
    int K, int M, int lda, int ldc, int act, int outfmt) {
  __shared__ float As[128 * 65];
  __shared__ float Ws[64 * 140 + 160];
  int tid = threadIdx.x;
  int tx = tid & 15, ty = tid >> 4;
  int rbase = blockIdx.x * 128;

  float acc[8][CT];
#pragma unroll
  for (int i = 0; i < 8; ++i)
#pragma unroll
    for (int j = 0; j < CT; ++j) acc[i][j] = 0.f;

  for (int k0 = 0; k0 < K; k0 += 64) {
    int kc = min(64, K - k0);
#pragma unroll
    for (int it = 0; it < 8; ++it) {
      int idx = tid + it * 256;
      int r = idx >> 4, q = idx & 15;
      float4 v = make_float4(0.f, 0.f, 0.f, 0.f);
      int row = rbase + r;
      if (row < N_NODES && q * 4 < kc)
        v = *(const float4*)&A[(size_t)row * lda + k0 + q * 4];
      float* dst = &As[r * 65 + q * 4];
      dst[0] = v.x; dst[1] = v.y; dst[2] = v.z; dst[3] = v.w;
    }
    for (int idx = tid; idx < kc * M; idx += 256)
      Ws[idx] = W[(size_t)k0 * M + idx];
    __syncthreads();

    for (int k = 0; k < kc; ++k) {
      float a[8];
#pragma unroll
      for (int i = 0; i < 8; ++i) a[i] = As[(ty * 8 + i) * 65 + k];
      float w[CT];
#pragma unroll
      for (int j = 0; j < CT; ++j) w[j] = Ws[k * M + tx * CT + j];
#pragma unroll
      for (int i = 0; i < 8; ++i)
#pragma unroll
        for (int j = 0; j < CT; ++j)
          acc[i][j] = fmaf(a[i], w[j], acc[i][j]);
    }
    __syncthreads();
  }

#pragma unroll
  for (int i = 0; i < 8; ++i) {
    int row = rbase + ty * 8 + i;
    if (row >= N_NODES) continue;
#pragma unroll
    for (int j = 0; j < CT; ++j) {
      int col = tx * CT + j;
      if (col >= M) continue;
      float c = acc[i][j];
      if (bias) c += bias[col];
      if (act) c = tanhf(c);
      if (outfmt == 0)
        ((float*)C)[(size_t)row * ldc + col] = c;
      else
        ((unsigned short*)C)[(size_t)row * ldc + col] = f2bf(c);
    }
  }
}

// ---------------- SPMM (bf16 in/out, fp32 accum) ---------------------------
// half-wave (32 lanes) per row; lane = 4-bf16 (8B) chunk of the row.
// Edge block of 32: coalesced (col,val) preload, __shfl broadcast, unrolled
// gathers for MLP.
template <int F>
__global__ __launch_bounds__(256) void spmm_bf16_kernel(
    const int* __restrict__ rowptr, const int* __restrict__ cols,
    const float* __restrict__ vals, const unsigned short* __restrict__ xin,
    unsigned short* __restrict__ xout) {
  constexpr int FQ = F / 4;  // uint2 (4 bf16) chunks per row
  int lane = threadIdx.x & 31;
  int r = blockIdx.x * 8 + (threadIdx.x >> 5);
  if (r >= N_NODES) return;
  int e0 = rowptr[r], e1 = rowptr[r + 1];
  int myoff = (lane < FQ) ? lane : 0;  // inactive lanes alias lane 0 (same line)
  const uint2* xin2 = (const uint2*)xin;

  float4 acc = make_float4(0.f, 0.f, 0.f, 0.f);
  int e = e0;
  // full 32-edge blocks
  while (e + 32 <= e1) {
    int   c_l = cols[e + lane];
    float v_l = vals[e + lane];
#pragma unroll 16
    for (int j = 0; j < 32; ++j) {
      int   c = __shfl(c_l, j, 32);
      float v = __shfl(v_l, j, 32);
      uint2 u = xin2[(size_t)c * FQ + myoff];
      acc.x = fmaf(v, __uint_as_float(u.x << 16), acc.x);
      acc.y = fmaf(v, __uint_as_float(u.x & 0xffff0000u), acc.y);
      acc.z = fmaf(v, __uint_as_float(u.y << 16), acc.z);
      acc.w = fmaf(v, __uint_as_float(u.y & 0xffff0000u), acc.w);
    }
    e += 32;
  }
  // tail
  int rem = e1 - e;
  if (rem > 0) {
    int   c_l = 0;
    float v_l = 0.f;
    if (lane < rem) { c_l = cols[e + lane]; v_l = vals[e + lane]; }
#pragma unroll 4
    for (int j = 0; j < rem; ++j) {
      int   c = __shfl(c_l, j, 32);
      float v = __shfl(v_l, j, 32);
      uint2 u = xin2[(size_t)c * FQ + myoff];
      acc.x = fmaf(v, __uint_as_float(u.x << 16), acc.x);
      acc.y = fmaf(v, __uint_as_float(u.x & 0xffff0000u), acc.y);
      acc.z = fmaf(v, __uint_as_float(u.y << 16), acc.z);
      acc.w = fmaf(v, __uint_as_float(u.y & 0xffff0000u), acc.w);
    }
  }
  if (lane < FQ) {
    uint2 o;
    o.x = (unsigned)f2bf(acc.x) | ((unsigned)f2bf(acc.y) << 16);
    o.y = (unsigned)f2bf(acc.z) | ((unsigned)f2bf(acc.w) << 16);
    ((uint2*)xout)[(size_t)r * FQ + lane] = o;
  }
}

// ---------------- bias + LayerNorm + tanh (bf16 in, fp32 out) --------------
template <int F>
__global__ __launch_bounds__(256) void bias_ln_tanh_kernel(
    const unsigned short* __restrict__ in, const float* __restrict__ bias,
    const float* __restrict__ g, const float* __restrict__ b,
    float* __restrict__ out) {
  int wid = threadIdx.x >> 6, lane = threadIdx.x & 63;
  int r = blockIdx.x * 4 + wid;
  if (r >= N_NODES) return;
  float x0 = 0.f, x1 = 0.f;
  if (lane < F)      x0 = bf2f(in[(size_t)r * F + lane]) + bias[lane];
  if (lane + 64 < F) x1 = bf2f(in[(size_t)r * F + lane + 64]) + bias[lane + 64];
  float s = x0 + x1, s2 = x0 * x0 + x1 * x1;
  for (int o = 32; o > 0; o >>= 1) {
    s  += __shfl_down(s, o, 64);
    s2 += __shfl_down(s2, o, 64);
  }
  s = __shfl(s, 0, 64); s2 = __shfl(s2, 0, 64);
  const float invF = 1.0f / (float)F;
  float mu = s * invF;
  float var = s2 * invF - mu * mu;
  float rs = rsqrtf(var + 1e-5f);
  if (lane < F)
    out[(size_t)r * F + lane] = tanhf((x0 - mu) * rs * g[lane] + b[lane]);
  if (lane + 64 < F)
    out[(size_t)r * F + lane + 64] =
        tanhf((x1 - mu) * rs * g[lane + 64] + b[lane + 64]);
}

// ---------------------------------------------------------------------------
extern "C" void kernel_launch(void* const* d_in, const int* in_sizes, int n_in,
                              void* d_out, int out_size, void* d_ws,
                              size_t ws_size, hipStream_t stream) {
  const float* x        = (const float*)d_in[0];
  const float* adj_vals = (const float*)d_in[1];
  const float* bn_g     = (const float*)d_in[2];
  const float* bn_b     = (const float*)d_in[3];
  const float* W_in     = (const float*)d_in[4];
  const float* b_in     = (const float*)d_in[5];
  const float* W1       = (const float*)d_in[6];
  const float* b1       = (const float*)d_in[7];
  const float* ln1_g    = (const float*)d_in[8];
  const float* ln1_b    = (const float*)d_in[9];
  const float* W2       = (const float*)d_in[10];
  const float* b2       = (const float*)d_in[11];
  const float* ln2_g    = (const float*)d_in[12];
  const float* ln2_b    = (const float*)d_in[13];
  const float* W_out    = (const float*)d_in[14];
  const float* b_out    = (const float*)d_in[15];
  const int*   adj_rows = (const int*)d_in[16];
  const int*   adj_cols = (const int*)d_in[17];
  float* out = (float*)d_out;

  // workspace layout
  float* ws      = (float*)d_ws;
  float* bn_sums = ws;                       // 512 floats
  float* Wf      = ws + 512;                 // 256*140
  float* bf      = Wf + 35840;               // 144
  int*   rowptr  = (int*)(bf + 144);         // 100016 ints
  float* buf0    = (float*)(rowptr + 100016);            // N*140 fp32
  unsigned short* zb = (unsigned short*)(buf0 + (size_t)N_NODES * 140); // N*120 bf16
  unsigned short* wb = zb + (size_t)N_NODES * 120;                      // N*120 bf16

  hipMemsetAsync(bn_sums, 0, 512 * sizeof(float), stream);
  bn_stats_kernel<<<1024, 256, 0, stream>>>(x, bn_sums);
  fold_bn_kernel<<<140, 256, 0, stream>>>(bn_sums, bn_g, bn_b, W_in, b_in, Wf, bf);
  build_rowptr_kernel<<<(N_NODES + 256) / 256, 256, 0, stream>>>(adj_rows, rowptr);

  const int gemm_grid = (N_NODES + 127) / 128;  // 782
  const int spmm_grid = (N_NODES + 7) / 8;      // 12500
  const int ln_grid   = (N_NODES + 3) / 4;      // 25000

  // t = tanh(bn(x) @ Wf + bf)       [N,140] fp32
  gemm_kernel<9><<<gemm_grid, 256, 0, stream>>>(x, Wf, bf, buf0, 256, 140, 256, 140, 1, 0);
  // z = t @ W1 (bias deferred)      [N,120] bf16
  gemm_kernel<8><<<gemm_grid, 256, 0, stream>>>(buf0, W1, nullptr, zb, 140, 120, 140, 120, 0, 1);
  // 4 hops at F=120 (bf16)
  spmm_bf16_kernel<120><<<spmm_grid, 256, 0, stream>>>(rowptr, adj_cols, adj_vals, zb, wb);
  spmm_bf16_kernel<120><<<spmm_grid, 256, 0, stream>>>(rowptr, adj_cols, adj_vals, wb, zb);
  spmm_bf16_kernel<120><<<spmm_grid, 256, 0, stream>>>(rowptr, adj_cols, adj_vals, zb, wb);
  spmm_bf16_kernel<120><<<spmm_grid, 256, 0, stream>>>(rowptr, adj_cols, adj_vals, wb, zb);
  // u = tanh(LN(z + b1))            [N,120] fp32
  bias_ln_tanh_kernel<120><<<ln_grid, 256, 0, stream>>>(zb, b1, ln1_g, ln1_b, buf0);
  // v = u @ W2 (bias deferred)      [N,100] bf16
  gemm_kernel<7><<<gemm_grid, 256, 0, stream>>>(buf0, W2, nullptr, zb, 120, 100, 120, 100, 0, 1);
  // 4 hops at F=100 (bf16)
  spmm_bf16_kernel<100><<<spmm_grid, 256, 0, stream>>>(rowptr, adj_cols, adj_vals, zb, wb);
  spmm_bf16_kernel<100><<<spmm_grid, 256, 0, stream>>>(rowptr, adj_cols, adj_vals, wb, zb);
  spmm_bf16_kernel<100><<<spmm_grid, 256, 0, stream>>>(rowptr, adj_cols, adj_vals, zb, wb);
  spmm_bf16_kernel<100><<<spmm_grid, 256, 0, stream>>>(rowptr, adj_cols, adj_vals, wb, zb);
  // w = tanh(LN(v + b2))            [N,100] fp32
  bias_ln_tanh_kernel<100><<<ln_grid, 256, 0, stream>>>(zb, b2, ln2_g, ln2_b, buf0);
  // out = w @ W_out + b_out         [N,64] fp32
  gemm_kernel<4><<<gemm_grid, 256, 0, stream>>>(buf0, W_out, b_out, out, 100, 64, 100, 64, 0, 0);
}

// Round 4
// 1747.678 us; speedup vs baseline: 1.4648x; 1.1307x over previous
//
#include <hip/hip_runtime.h>
#include <hip/hip_bf16.h>
#include <math.h>

#define N_NODES 100000
#define E_EDGES 3200000
#define IN_DIM  256

typedef __attribute__((ext_vector_type(8))) short bf16x8;
typedef __attribute__((ext_vector_type(4))) float f32x4;

// ---- bf16 helpers ---------------------------------------------------------
__device__ __forceinline__ unsigned short f2bf(float f) {
  unsigned u = __float_as_uint(f);
  u += 0x7fffu + ((u >> 16) & 1u);   // RTNE
  return (unsigned short)(u >> 16);
}
__device__ __forceinline__ float bf2f(unsigned short h) {
  return __uint_as_float(((unsigned)h) << 16);
}

// ---------------- BN column stats (sum, sumsq per feature) ----------------
__global__ __launch_bounds__(256) void bn_stats_kernel(
    const float* __restrict__ x, float* __restrict__ sums /*512 floats*/) {
  int c = threadIdx.x;
  float s = 0.f, s2 = 0.f;
  for (int r = blockIdx.x; r < N_NODES; r += gridDim.x) {
    float v = x[(size_t)r * IN_DIM + c];
    s += v; s2 += v * v;
  }
  atomicAdd(&sums[c], s);
  atomicAdd(&sums[256 + c], s2);
}

// ------------- fold BN affine into W_in / b_in ----------------------------
__global__ __launch_bounds__(256) void fold_bn_kernel(
    const float* __restrict__ sums, const float* __restrict__ bn_g,
    const float* __restrict__ bn_b, const float* __restrict__ W_in,
    const float* __restrict__ b_in, float* __restrict__ Wf,
    float* __restrict__ bf) {
  int j = blockIdx.x;   // out col 0..139
  int c = threadIdx.x;  // in col 0..255
  const float invN = 1.0f / (float)N_NODES;
  float mu  = sums[c] * invN;
  float var = sums[256 + c] * invN - mu * mu;
  float s   = bn_g[c] * rsqrtf(var + 1e-5f);
  float t   = bn_b[c] - mu * s;
  float w   = W_in[(size_t)c * 140 + j];
  Wf[(size_t)c * 140 + j] = s * w;
  float v = t * w;
  for (int o = 32; o > 0; o >>= 1) v += __shfl_down(v, o, 64);
  __shared__ float red[4];
  int wid = threadIdx.x >> 6, lane = threadIdx.x & 63;
  if (lane == 0) red[wid] = v;
  __syncthreads();
  if (threadIdx.x == 0)
    bf[j] = b_in[j] + red[0] + red[1] + red[2] + red[3];
}

// ---------------- CSR row_ptr from sorted rows (binary search) -------------
__global__ __launch_bounds__(256) void build_rowptr_kernel(
    const int* __restrict__ rows, int* __restrict__ rowptr) {
  int r = blockIdx.x * 256 + threadIdx.x;
  if (r > N_NODES) return;
  int lo = 0, hi = E_EDGES;
  while (lo < hi) {
    int mid = (lo + hi) >> 1;
    if (rows[mid] < r) lo = mid + 1; else hi = mid;
  }
  rowptr[r] = lo;
}

// ------- pack fp32 W[K,M] into MFMA B-fragment order, bf16, zero-padded ----
// Bp[(kt*NT + nt)*64 + lane] = uint4 of 8 bf16: B[kt*32+(lane>>4)*8+j][nt*16+(lane&15)]
__global__ __launch_bounds__(256) void pack_w_kernel(
    const float* __restrict__ W, uint4* __restrict__ Bp, int K, int M, int NT,
    int total) {
  int id = blockIdx.x * 256 + threadIdx.x;
  if (id >= total) return;
  int lane = id & 63;
  int nt = (id >> 6) % NT;
  int kt = id / (64 * NT);
  int n = nt * 16 + (lane & 15);
  int kbase = kt * 32 + (lane >> 4) * 8;
  unsigned short v[8];
#pragma unroll
  for (int j = 0; j < 8; ++j) {
    int k = kbase + j;
    v[j] = (k < K && n < M) ? f2bf(W[(size_t)k * M + n]) : (unsigned short)0;
  }
  Bp[id] = *(uint4*)v;
}

// ---------------- MFMA bf16 GEMM -------------------------------------------
// C[N, ldc] = act(A[N, KPAD] @ B[KPAD, NT*16] + bias); A fp32 or bf16.
// KPAD must be a multiple of 64. 256 thr = 4 waves; block tile 128 rows.
template <int KPAD, int NT, typename AT>
__global__ __launch_bounds__(256) void mfma_gemm_kernel(
    const AT* __restrict__ A, const uint4* __restrict__ Bp,
    const float* __restrict__ bias, void* __restrict__ C,
    int M, int Mstore, int ldc, int act, int outfmt) {
  static_assert(KPAD % 64 == 0, "KPAD must be a multiple of 64");
  __shared__ unsigned short As[128 * 72];  // 64-k chunk, stride 72 (2-way only)
  int tid = threadIdx.x;
  int lane = tid & 63;
  int wave = tid >> 6;
  int quad = lane >> 4, m16 = lane & 15;
  int rbase = blockIdx.x * 128;
  int wrow = wave * 32;

  f32x4 acc[2][NT];
#pragma unroll
  for (int mt = 0; mt < 2; ++mt)
#pragma unroll
    for (int nt = 0; nt < NT; ++nt)
      acc[mt][nt] = (f32x4){0.f, 0.f, 0.f, 0.f};

  for (int k0 = 0; k0 < KPAD; k0 += 64) {
    if constexpr (sizeof(AT) == 2) {
      int r0 = tid >> 3, q = tid & 7;
#pragma unroll
      for (int it = 0; it < 4; ++it) {
        int r = r0 + it * 32;
        int row = rbase + r;
        uint4 v = make_uint4(0u, 0u, 0u, 0u);
        if (row < N_NODES)
          v = *(const uint4*)((const unsigned short*)A + (size_t)row * KPAD + k0 + q * 8);
        *(uint4*)&As[r * 72 + q * 8] = v;
      }
    } else {
      int r0 = tid >> 4, fq = tid & 15;
#pragma unroll
      for (int it = 0; it < 8; ++it) {
        int r = r0 + it * 16;
        int row = rbase + r;
        float4 v = make_float4(0.f, 0.f, 0.f, 0.f);
        if (row < N_NODES)
          v = *(const float4*)((const float*)A + (size_t)row * KPAD + k0 + fq * 4);
        unsigned short p[4] = {f2bf(v.x), f2bf(v.y), f2bf(v.z), f2bf(v.w)};
        *(uint2*)&As[r * 72 + fq * 4] = *(uint2*)p;
      }
    }
    __syncthreads();
#pragma unroll
    for (int s = 0; s < 2; ++s) {
      int kt = (k0 >> 5) + s;
      bf16x8 a0 = *(const bf16x8*)&As[(wrow + m16) * 72 + s * 32 + quad * 8];
      bf16x8 a1 = *(const bf16x8*)&As[(wrow + 16 + m16) * 72 + s * 32 + quad * 8];
#pragma unroll
      for (int nt = 0; nt < NT; ++nt) {
        uint4 bw = Bp[(size_t)(kt * NT + nt) * 64 + lane];
        bf16x8 b = *(const bf16x8*)&bw;
        acc[0][nt] = __builtin_amdgcn_mfma_f32_16x16x32_bf16(a0, b, acc[0][nt], 0, 0, 0);
        acc[1][nt] = __builtin_amdgcn_mfma_f32_16x16x32_bf16(a1, b, acc[1][nt], 0, 0, 0);
      }
    }
    __syncthreads();
  }

  // epilogue: C/D layout col=lane&15, row=quad*4+reg
#pragma unroll
  for (int mt = 0; mt < 2; ++mt)
#pragma unroll
    for (int nt = 0; nt < NT; ++nt)
#pragma unroll
      for (int i = 0; i < 4; ++i) {
        int row = rbase + wrow + mt * 16 + quad * 4 + i;
        int col = nt * 16 + m16;
        if (row >= N_NODES || col >= Mstore) continue;
        float c = acc[mt][nt][i];
        if (col < M) {
          if (bias) c += bias[col];
          if (act) c = tanhf(c);
        } else {
          c = 0.f;  // zero pad for downstream K-padding
        }
        if (outfmt == 0)
          ((float*)C)[(size_t)row * ldc + col] = c;
        else
          ((unsigned short*)C)[(size_t)row * ldc + col] = f2bf(c);
      }
}

// ---------------- SPMM (bf16 in/out, fp32 accum) ---------------------------
template <int F>
__global__ __launch_bounds__(256) void spmm_bf16_kernel(
    const int* __restrict__ rowptr, const int* __restrict__ cols,
    const float* __restrict__ vals, const unsigned short* __restrict__ xin,
    unsigned short* __restrict__ xout) {
  constexpr int FQ = F / 4;  // uint2 (4 bf16) chunks per row
  int lane = threadIdx.x & 31;
  int r = blockIdx.x * 8 + (threadIdx.x >> 5);
  if (r >= N_NODES) return;
  int e0 = rowptr[r], e1 = rowptr[r + 1];
  int myoff = (lane < FQ) ? lane : 0;
  const uint2* xin2 = (const uint2*)xin;

  float4 acc = make_float4(0.f, 0.f, 0.f, 0.f);
  int e = e0;
  while (e + 32 <= e1) {
    int   c_l = cols[e + lane];
    float v_l = vals[e + lane];
#pragma unroll 16
    for (int j = 0; j < 32; ++j) {
      int   c = __shfl(c_l, j, 32);
      float v = __shfl(v_l, j, 32);
      uint2 u = xin2[(size_t)c * FQ + myoff];
      acc.x = fmaf(v, __uint_as_float(u.x << 16), acc.x);
      acc.y = fmaf(v, __uint_as_float(u.x & 0xffff0000u), acc.y);
      acc.z = fmaf(v, __uint_as_float(u.y << 16), acc.z);
      acc.w = fmaf(v, __uint_as_float(u.y & 0xffff0000u), acc.w);
    }
    e += 32;
  }
  int rem = e1 - e;
  if (rem > 0) {
    int   c_l = 0;
    float v_l = 0.f;
    if (lane < rem) { c_l = cols[e + lane]; v_l = vals[e + lane]; }
#pragma unroll 4
    for (int j = 0; j < rem; ++j) {
      int   c = __shfl(c_l, j, 32);
      float v = __shfl(v_l, j, 32);
      uint2 u = xin2[(size_t)c * FQ + myoff];
      acc.x = fmaf(v, __uint_as_float(u.x << 16), acc.x);
      acc.y = fmaf(v, __uint_as_float(u.x & 0xffff0000u), acc.y);
      acc.z = fmaf(v, __uint_as_float(u.y << 16), acc.z);
      acc.w = fmaf(v, __uint_as_float(u.y & 0xffff0000u), acc.w);
    }
  }
  if (lane < FQ) {
    uint2 o;
    o.x = (unsigned)f2bf(acc.x) | ((unsigned)f2bf(acc.y) << 16);
    o.y = (unsigned)f2bf(acc.z) | ((unsigned)f2bf(acc.w) << 16);
    ((uint2*)xout)[(size_t)r * FQ + lane] = o;
  }
}

// -------- bias + LayerNorm + tanh (bf16 in, bf16 out, zero-padded) ---------
template <int F, int LDOUT>
__global__ __launch_bounds__(256) void bias_ln_tanh_kernel(
    const unsigned short* __restrict__ in, const float* __restrict__ bias,
    const float* __restrict__ g, const float* __restrict__ b,
    unsigned short* __restrict__ out) {
  int wid = threadIdx.x >> 6, lane = threadIdx.x & 63;
  int r = blockIdx.x * 4 + wid;
  if (r >= N_NODES) return;
  float x0 = 0.f, x1 = 0.f;
  if (lane < F)      x0 = bf2f(in[(size_t)r * F + lane]) + bias[lane];
  if (lane + 64 < F) x1 = bf2f(in[(size_t)r * F + lane + 64]) + bias[lane + 64];
  float s = x0 + x1, s2 = x0 * x0 + x1 * x1;
  for (int o = 32; o > 0; o >>= 1) {
    s  += __shfl_down(s, o, 64);
    s2 += __shfl_down(s2, o, 64);
  }
  s = __shfl(s, 0, 64); s2 = __shfl(s2, 0, 64);
  const float invF = 1.0f / (float)F;
  float mu = s * invF;
  float var = s2 * invF - mu * mu;
  float rs = rsqrtf(var + 1e-5f);
  if (lane < F)
    out[(size_t)r * LDOUT + lane] = f2bf(tanhf((x0 - mu) * rs * g[lane] + b[lane]));
  int c2 = lane + 64;
  if (c2 < F)
    out[(size_t)r * LDOUT + c2] = f2bf(tanhf((x1 - mu) * rs * g[c2] + b[c2]));
  else if (c2 < LDOUT)
    out[(size_t)r * LDOUT + c2] = 0;
}

// ---------------------------------------------------------------------------
extern "C" void kernel_launch(void* const* d_in, const int* in_sizes, int n_in,
                              void* d_out, int out_size, void* d_ws,
                              size_t ws_size, hipStream_t stream) {
  const float* x        = (const float*)d_in[0];
  const float* adj_vals = (const float*)d_in[1];
  const float* bn_g     = (const float*)d_in[2];
  const float* bn_b     = (const float*)d_in[3];
  const float* W_in     = (const float*)d_in[4];
  const float* b_in     = (const float*)d_in[5];
  const float* W1       = (const float*)d_in[6];
  const float* b1       = (const float*)d_in[7];
  const float* ln1_g    = (const float*)d_in[8];
  const float* ln1_b    = (const float*)d_in[9];
  const float* W2       = (const float*)d_in[10];
  const float* b2       = (const float*)d_in[11];
  const float* ln2_g    = (const float*)d_in[12];
  const float* ln2_b    = (const float*)d_in[13];
  const float* W_out    = (const float*)d_in[14];
  const float* b_out    = (const float*)d_in[15];
  const int*   adj_rows = (const int*)d_in[16];
  const int*   adj_cols = (const int*)d_in[17];
  float* out = (float*)d_out;

  // workspace layout (bytes)
  char* wsb = (char*)d_ws;
  size_t off = 0;
  auto alloc = [&](size_t bytes) { void* p = wsb + off; off += (bytes + 255) & ~255ull; return p; };
  float* bn_sums = (float*)alloc(512 * 4);
  float* Wf      = (float*)alloc(35840 * 4);
  float* bf      = (float*)alloc(144 * 4);
  int*   rowptr  = (int*)alloc(100016 * 4);
  uint4* Bp1 = (uint4*)alloc(8 * 10 * 64 * 16);  // K=256: 8 ktiles, NT=10
  uint4* Bp2 = (uint4*)alloc(6 * 8 * 64 * 16);   // K=192: 6 ktiles, NT=8 (real K=140)
  uint4* Bp3 = (uint4*)alloc(4 * 7 * 64 * 16);   // K=128: 4 ktiles, NT=7
  uint4* Bp4 = (uint4*)alloc(4 * 4 * 64 * 16);   // K=128: 4 ktiles, NT=4
  unsigned short* h1  = (unsigned short*)alloc((size_t)N_NODES * 192 * 2);  // [N,192]; later LN outs [N,128]
  unsigned short* zb  = (unsigned short*)alloc((size_t)N_NODES * 120 * 2);
  unsigned short* wb  = (unsigned short*)alloc((size_t)N_NODES * 120 * 2);
  unsigned short* lnb = h1;  // reuse: h1 dead after GEMM2

  hipMemsetAsync(bn_sums, 0, 512 * sizeof(float), stream);
  hipMemsetAsync(h1, 0, (size_t)N_NODES * 192 * 2, stream);  // cols 160..191 must be 0
  bn_stats_kernel<<<1024, 256, 0, stream>>>(x, bn_sums);
  fold_bn_kernel<<<140, 256, 0, stream>>>(bn_sums, bn_g, bn_b, W_in, b_in, Wf, bf);
  build_rowptr_kernel<<<(N_NODES + 256) / 256, 256, 0, stream>>>(adj_rows, rowptr);
  // pack weights
  pack_w_kernel<<<(8 * 10 * 64 + 255) / 256, 256, 0, stream>>>(Wf,    Bp1, 256, 140, 10, 8 * 10 * 64);
  pack_w_kernel<<<(6 * 8 * 64 + 255) / 256, 256, 0, stream>>>(W1,    Bp2, 140, 120, 8,  6 * 8 * 64);
  pack_w_kernel<<<(4 * 7 * 64 + 255) / 256, 256, 0, stream>>>(W2,    Bp3, 120, 100, 7,  4 * 7 * 64);
  pack_w_kernel<<<(4 * 4 * 64 + 255) / 256, 256, 0, stream>>>(W_out, Bp4, 100, 64,  4,  4 * 4 * 64);

  const int gemm_grid = (N_NODES + 127) / 128;  // 782
  const int spmm_grid = (N_NODES + 7) / 8;      // 12500
  const int ln_grid   = (N_NODES + 3) / 4;      // 25000

  // h1 = tanh(bn(x) @ Wf + bf)  [N,192] bf16; cols 140..159 zeroed here, 160..191 by memset
  mfma_gemm_kernel<256, 10, float><<<gemm_grid, 256, 0, stream>>>(
      x, Bp1, bf, h1, 140, 160, 192, 1, 1);
  // zb = h1 @ W1 (bias deferred)  [N,120] bf16   (KPAD=192, multiple of 64)
  mfma_gemm_kernel<192, 8, unsigned short><<<gemm_grid, 256, 0, stream>>>(
      h1, Bp2, nullptr, zb, 120, 120, 120, 0, 1);
  // 4 hops at F=120
  spmm_bf16_kernel<120><<<spmm_grid, 256, 0, stream>>>(rowptr, adj_cols, adj_vals, zb, wb);
  spmm_bf16_kernel<120><<<spmm_grid, 256, 0, stream>>>(rowptr, adj_cols, adj_vals, wb, zb);
  spmm_bf16_kernel<120><<<spmm_grid, 256, 0, stream>>>(rowptr, adj_cols, adj_vals, zb, wb);
  spmm_bf16_kernel<120><<<spmm_grid, 256, 0, stream>>>(rowptr, adj_cols, adj_vals, wb, zb);
  // lnb = tanh(LN(zb + b1))  [N,128] bf16, cols 120..127 = 0
  bias_ln_tanh_kernel<120, 128><<<ln_grid, 256, 0, stream>>>(zb, b1, ln1_g, ln1_b, lnb);
  // zb = lnb @ W2 (bias deferred)  [N,100] bf16
  mfma_gemm_kernel<128, 7, unsigned short><<<gemm_grid, 256, 0, stream>>>(
      lnb, Bp3, nullptr, zb, 100, 100, 100, 0, 1);
  // 4 hops at F=100
  spmm_bf16_kernel<100><<<spmm_grid, 256, 0, stream>>>(rowptr, adj_cols, adj_vals, zb, wb);
  spmm_bf16_kernel<100><<<spmm_grid, 256, 0, stream>>>(rowptr, adj_cols, adj_vals, wb, zb);
  spmm_bf16_kernel<100><<<spmm_grid, 256, 0, stream>>>(rowptr, adj_cols, adj_vals, zb, wb);
  spmm_bf16_kernel<100><<<spmm_grid, 256, 0, stream>>>(rowptr, adj_cols, adj_vals, wb, zb);
  // lnb = tanh(LN(zb + b2))  [N,128] bf16, cols 100..127 = 0
  bias_ln_tanh_kernel<100, 128><<<ln_grid, 256, 0, stream>>>(zb, b2, ln2_g, ln2_b, lnb);
  // out = lnb @ W_out + b_out  [N,64] fp32
  mfma_gemm_kernel<128, 4, unsigned short><<<gemm_grid, 256, 0, stream>>>(
      lnb, Bp4, b_out, out, 64, 64, 64, 0, 0);
}